// Round 5
// baseline (439.416 us; speedup 1.0000x reference)
//
#include <hip/hip_runtime.h>

// LengthRegulator — DIAGNOSTIC build (v4).
// Round 0/2/4 facts: three structurally different kernels (binary search /
// LDS scatter / branchless+swizzle+NT) ALL measure 269.8-271.8us, while the
// rocprof top-5 shows only ~146-150us harness poison-fills and never this
// kernel => kernel GPU time < 145us, dur_us contains a ~150us fixed fill.
// Inferred copy cost ~122us vs ~42us write roofline — unexplained and
// invariant. This build repeats the (idempotent) copy phase REP=4 times to
//   (a) lift the kernel above the top-5 cutoff so its own counters
//       (hbm_gbps, FETCH_SIZE, WRITE_SIZE, VALUBusy, Occupancy) surface, and
//   (b) measure copy-pass time = (dur_us - 269.8)/3.
// Output remains exactly correct (same values stored each pass).

#define BB 64
#define LL 256
#define DD 512
#define TT 1792
#define D4 (DD / 4)          // 128 float4 per row
#define TILE 64              // frames per block; TT = 28 * TILE exact
#define NBT (TT / TILE)      // 28 t-blocks per b
#define NBLK (BB * NBT)      // 1792 blocks
#define REP 4                // diagnostic: copy phase repeated (idempotent)

typedef float f32x4 __attribute__((ext_vector_type(4)));

__global__ __launch_bounds__(256) void length_regulator_kernel(
    const f32x4* __restrict__ x4,       // [B, L, D4]
    const int*   __restrict__ dur,      // [B, L]
    const int*   __restrict__ maxlen,   // [1]
    float*       __restrict__ out)      // [B*T*D + 1]
{
    __shared__ int cum[LL];
    __shared__ int idx_s[TILE];
    const int tid = threadIdx.x;

    // XCD-locality swizzle: XCD k owns b in [8k, 8k+8) -> 4MB x-panel per L2.
    const int bid  = blockIdx.x;
    const int virt = (bid & 7) * (NBLK / 8) + (bid >> 3);
    const int b    = virt / NBT;
    const int t0   = (virt % NBT) * TILE;

    // --- inclusive scan of durations for row b (Hillis-Steele, 8 steps) ---
    // ALPHA = 1.0 -> round(d * 1.0) == d
    cum[tid] = dur[b * LL + tid];
    if (tid < TILE) idx_s[tid] = -1;  // -1 = "zero frame" (t >= total)
    __syncthreads();
    #pragma unroll
    for (int off = 1; off < LL; off <<= 1) {
        int v = (tid >= off) ? cum[tid - off] : 0;
        __syncthreads();
        cum[tid] += v;
        __syncthreads();
    }
    // all-zero row: d[0] = 1 -> cum[j] = 1 for all j
    if (cum[LL - 1] == 0) cum[tid] = 1;
    __syncthreads();

    // --- scatter: thread j stamps its phoneme index over [cum[j-1], cum[j]) ---
    // Reproduces searchsorted(cum, t, 'right'). O(duration) <= 7 LDS writes.
    {
        const int end   = cum[tid];
        const int start = (tid > 0) ? cum[tid - 1] : 0;
        const int lo = max(start, t0);
        const int hi = min(end, t0 + TILE);
        for (int t = lo; t < hi; ++t) idx_s[t - t0] = tid;
    }
    __syncthreads();

    // --- copy phase, repeated REP times (idempotent; diagnostic only) ---
    const int group = tid >> 7;   // 0..1
    const int lane  = tid & 127;  // float4 index within row
    const f32x4 z   = (f32x4)(0.f);
    const f32x4* __restrict__ xrow = x4 + (size_t)b * LL * D4;
    f32x4* __restrict__ outb = (f32x4*)out + ((size_t)b * TT + t0) * D4;

    #pragma unroll 1
    for (int rep = 0; rep < REP; ++rep) {
        #pragma unroll
        for (int it = 0; it < TILE / 2; ++it) {
            const int toff = it * 2 + group;     // frame offset within tile
            const int id   = idx_s[toff];        // uniform per wave
            const int idc  = (id >= 0) ? id : 0; // clamp: always a valid row
            f32x4 v = xrow[idc * D4 + lane];
            v = (id >= 0) ? v : z;               // select, no branch
            __builtin_nontemporal_store(v, outb + toff * D4 + lane);
        }
        // compiler-level memory barrier: forbids dead-store elimination of
        // earlier passes; no runtime cost.
        asm volatile("" ::: "memory");
    }

    // --- output 1: max_length as float, one thread writes it ---
    if (virt == 0 && tid == 0) {
        out[(size_t)BB * TT * DD] = (float)maxlen[0];
    }
}

extern "C" void kernel_launch(void* const* d_in, const int* in_sizes, int n_in,
                              void* d_out, int out_size, void* d_ws, size_t ws_size,
                              hipStream_t stream) {
    const f32x4* x4  = (const f32x4*)d_in[0];
    const int*   dur = (const int*)d_in[1];
    const int*   ml  = (const int*)d_in[2];
    float*       out = (float*)d_out;

    length_regulator_kernel<<<dim3(NBLK), dim3(256), 0, stream>>>(x4, dur, ml, out);
}

// Round 6
// 263.703 us; speedup vs baseline: 1.6663x; 1.6663x over previous
//
#include <hip/hip_runtime.h>

// LengthRegulator: expand x[B,L,D] along L per integer durations into out[B,T,D].
// B=64, L=256, D=512, T=max_length=1792. Out: (out [B,T,D] f32, max_length).
//
// v5: Round-5 diagnostic (REP=4) measured: NT-store path = 4.16 TB/s
// (56.5us/pass for 235MB), while the harness fill writes the SAME buffer at
// 6.4 TB/s with normal stores. FETCH_SIZE=19MB total proved x is fully
// cache-resident (gather never mattered) and fill's FETCH~0 proved full-line
// normal stores do no RFO. So: drop nontemporal (its L2-protection rationale
// is moot), use plain stores through L2 writeback; batch the copy loop 4-wide
// so the VGPR budget stops capping loads-in-flight.
// Kernel ~74us -> predict ~50-58us (write roofline ~42us + scan).

#define BB 64
#define LL 256
#define DD 512
#define TT 1792
#define D4 (DD / 4)          // 128 float4 per row
#define TILE 64              // frames per block; TT = 28 * TILE exact
#define NBT (TT / TILE)      // 28 t-blocks per b
#define NBLK (BB * NBT)      // 1792 blocks

typedef float f32x4 __attribute__((ext_vector_type(4)));

__global__ __launch_bounds__(256) void length_regulator_kernel(
    const f32x4* __restrict__ x4,       // [B, L, D4]
    const int*   __restrict__ dur,      // [B, L]
    const int*   __restrict__ maxlen,   // [1]
    float*       __restrict__ out)      // [B*T*D + 1]
{
    __shared__ int cum[LL];
    __shared__ int idx_s[TILE];
    const int tid = threadIdx.x;

    // XCD-locality swizzle: XCD k owns b in [8k, 8k+8) -> 4MB x-panel per L2.
    const int bid  = blockIdx.x;
    const int virt = (bid & 7) * (NBLK / 8) + (bid >> 3);
    const int b    = virt / NBT;
    const int t0   = (virt % NBT) * TILE;

    // --- inclusive scan of durations for row b (Hillis-Steele, 8 steps) ---
    // ALPHA = 1.0 -> round(d * 1.0) == d
    cum[tid] = dur[b * LL + tid];
    if (tid < TILE) idx_s[tid] = -1;  // -1 = "zero frame" (t >= total)
    __syncthreads();
    #pragma unroll
    for (int off = 1; off < LL; off <<= 1) {
        int v = (tid >= off) ? cum[tid - off] : 0;
        __syncthreads();
        cum[tid] += v;
        __syncthreads();
    }
    // all-zero row: d[0] = 1 -> cum[j] = 1 for all j
    if (cum[LL - 1] == 0) cum[tid] = 1;
    __syncthreads();

    // --- scatter: thread j stamps its phoneme index over [cum[j-1], cum[j]) ---
    // Reproduces searchsorted(cum, t, 'right'). O(duration) <= 7 LDS writes.
    {
        const int end   = cum[tid];
        const int start = (tid > 0) ? cum[tid - 1] : 0;
        const int lo = max(start, t0);
        const int hi = min(end, t0 + TILE);
        for (int t = lo; t < hi; ++t) idx_s[t - t0] = tid;
    }
    __syncthreads();

    // --- copy: 2 groups x 128 lanes; one D-row per group per iter ---
    // Batch-4: 4 independent loads in flight before 4 stores (all indices
    // compile-time after full unroll -> registers, no scratch).
    const int group = tid >> 7;   // 0..1
    const int lane  = tid & 127;  // float4 index within row
    const f32x4 z   = (f32x4)(0.f);
    const f32x4* __restrict__ xrow = x4 + (size_t)b * LL * D4;
    f32x4* __restrict__ outb = (f32x4*)out + ((size_t)b * TT + t0) * D4;

    #pragma unroll
    for (int itb = 0; itb < TILE / 2; itb += 4) {
        const int ta = (itb + 0) * 2 + group;
        const int tb = (itb + 1) * 2 + group;
        const int tc = (itb + 2) * 2 + group;
        const int td = (itb + 3) * 2 + group;
        const int ia = idx_s[ta];
        const int ib = idx_s[tb];
        const int ic = idx_s[tc];
        const int ie = idx_s[td];
        f32x4 va = xrow[max(ia, 0) * D4 + lane];
        f32x4 vb = xrow[max(ib, 0) * D4 + lane];
        f32x4 vc = xrow[max(ic, 0) * D4 + lane];
        f32x4 ve = xrow[max(ie, 0) * D4 + lane];
        va = (ia >= 0) ? va : z;
        vb = (ib >= 0) ? vb : z;
        vc = (ic >= 0) ? vc : z;
        ve = (ie >= 0) ? ve : z;
        outb[ta * D4 + lane] = va;
        outb[tb * D4 + lane] = vb;
        outb[tc * D4 + lane] = vc;
        outb[td * D4 + lane] = ve;
    }

    // --- output 1: max_length as float, one thread writes it ---
    if (virt == 0 && tid == 0) {
        out[(size_t)BB * TT * DD] = (float)maxlen[0];
    }
}

extern "C" void kernel_launch(void* const* d_in, const int* in_sizes, int n_in,
                              void* d_out, int out_size, void* d_ws, size_t ws_size,
                              hipStream_t stream) {
    const f32x4* x4  = (const f32x4*)d_in[0];
    const int*   dur = (const int*)d_in[1];
    const int*   ml  = (const int*)d_in[2];
    float*       out = (float*)d_out;

    length_regulator_kernel<<<dim3(NBLK), dim3(256), 0, stream>>>(x4, dur, ml, out);
}